// Round 1
// baseline (124.127 us; speedup 1.0000x reference)
//
#include <hip/hip_runtime.h>

// ws layout: ws[0] = float loss accumulator, ((int*)ws)[1] = int total_len accumulator.

#define POS_PER_THREAD 4          // 2 float4-pairs per array
#define BLOCK 256
#define POS_PER_BLOCK (BLOCK * POS_PER_THREAD)   // 1024 positions

__global__ __launch_bounds__(BLOCK) void ce_main(
    const float* __restrict__ y_true,
    const float* __restrict__ y_pred,
    const int*   __restrict__ doc_len,
    float*       __restrict__ ws,
    int L, int chunks_per_row)
{
    const int b     = blockIdx.x / chunks_per_row;
    const int chunk = blockIdx.x % chunks_per_row;
    const int dl    = doc_len[b];   // uniform -> scalar load, L2-cached

    // exact total_len accumulation: one thread per row
    if (chunk == 0 && threadIdx.x == 0) {
        atomicAdd(((int*)ws) + 1, dl);
    }

    const int start = chunk * POS_PER_BLOCK;
    if (start >= dl) return;        // whole chunk past doc end: skip all loads

    const size_t row_base = (size_t)b * L;
    float local = 0.0f;

    #pragma unroll
    for (int j = 0; j < POS_PER_THREAD / 2; ++j) {
        const int pos = start + j * (BLOCK * 2) + (int)threadIdx.x * 2;
        if (pos < dl) {
            const size_t e = (row_base + (size_t)pos) * 2;   // float index, 16B aligned
            const float4 t = *(const float4*)(y_true + e);
            const float4 p = *(const float4*)(y_pred + e);
            // position pos (always valid here): one-hot -> exactly one term fires
            local += t.x * (-__logf(p.x)) + t.y * (-__logf(p.y));
            if (pos + 1 < dl) {
                local += t.z * (-__logf(p.z)) + t.w * (-__logf(p.w));
            }
        }
    }

    // wave-64 butterfly reduce
    for (int off = 32; off > 0; off >>= 1)
        local += __shfl_down(local, off, 64);

    __shared__ float wsum[BLOCK / 64];
    const int lane = threadIdx.x & 63;
    const int wid  = threadIdx.x >> 6;
    if (lane == 0) wsum[wid] = local;
    __syncthreads();
    if (threadIdx.x == 0) {
        float s = 0.0f;
        #pragma unroll
        for (int w = 0; w < BLOCK / 64; ++w) s += wsum[w];
        atomicAdd(ws, s);
    }
}

__global__ void ce_finalize(const float* __restrict__ ws, float* __restrict__ out)
{
    const int total = ((const int*)ws)[1];
    out[0] = ws[0] / (float)total;
}

extern "C" void kernel_launch(void* const* d_in, const int* in_sizes, int n_in,
                              void* d_out, int out_size, void* d_ws, size_t ws_size,
                              hipStream_t stream)
{
    const float* y_true  = (const float*)d_in[0];
    const float* y_pred  = (const float*)d_in[1];
    const int*   doc_len = (const int*)d_in[2];
    float*       out     = (float*)d_out;
    float*       ws      = (float*)d_ws;

    const int B = in_sizes[2];
    const int L = in_sizes[0] / (2 * B);
    const int chunks_per_row = (L + POS_PER_BLOCK - 1) / POS_PER_BLOCK;

    // zero the two accumulators (ws is poisoned 0xAA before every launch)
    hipMemsetAsync(ws, 0, 2 * sizeof(float), stream);

    dim3 grid(B * chunks_per_row);
    ce_main<<<grid, BLOCK, 0, stream>>>(y_true, y_pred, doc_len, ws, L, chunks_per_row);
    ce_finalize<<<1, 1, 0, stream>>>(ws, out);
}

// Round 2
// 97.653 us; speedup vs baseline: 1.2711x; 1.2711x over previous
//
#include <hip/hip_runtime.h>

// ws layout: ws[0 .. NPART-1] = per-block float partial losses (every block writes its slot).

#define BLOCK 256
#define POS_PER_THREAD 4
#define POS_PER_BLOCK (BLOCK * POS_PER_THREAD)   // 1024 positions per block

__global__ __launch_bounds__(BLOCK) void ce_main(
    const float* __restrict__ y_true,
    const float* __restrict__ y_pred,
    const int*   __restrict__ doc_len,
    float*       __restrict__ partials,
    int L, int chunks_per_row)
{
    const int b     = blockIdx.x / chunks_per_row;
    const int chunk = blockIdx.x % chunks_per_row;
    const int dl    = doc_len[b];                 // wave-uniform scalar load

    const int start = chunk * POS_PER_BLOCK;
    if (start >= dl) {
        // whole chunk past doc end: no loads, but must still define our slot
        if (threadIdx.x == 0) partials[blockIdx.x] = 0.0f;
        return;
    }

    const size_t row_base = (size_t)b * L;
    float local = 0.0f;

    #pragma unroll
    for (int j = 0; j < POS_PER_THREAD / 2; ++j) {
        const int pos = start + j * (BLOCK * 2) + (int)threadIdx.x * 2;
        if (pos < dl) {
            const size_t e = (row_base + (size_t)pos) * 2;   // float index, 16B aligned
            const float4 t = *(const float4*)(y_true + e);
            const float4 p = *(const float4*)(y_pred + e);
            // one-hot: exactly one of (t.x,t.y) is 1 -> branchless FMA
            local += t.x * (-__logf(p.x)) + t.y * (-__logf(p.y));
            if (pos + 1 < dl) {
                local += t.z * (-__logf(p.z)) + t.w * (-__logf(p.w));
            }
        }
    }

    // wave-64 butterfly reduce
    #pragma unroll
    for (int off = 32; off > 0; off >>= 1)
        local += __shfl_down(local, off, 64);

    __shared__ float wsum[BLOCK / 64];
    const int lane = threadIdx.x & 63;
    const int wid  = threadIdx.x >> 6;
    if (lane == 0) wsum[wid] = local;
    __syncthreads();
    if (threadIdx.x == 0) {
        float s = 0.0f;
        #pragma unroll
        for (int w = 0; w < BLOCK / 64; ++w) s += wsum[w];
        partials[blockIdx.x] = s;
    }
}

__global__ __launch_bounds__(BLOCK) void ce_finalize(
    const float* __restrict__ partials, int npart,
    const int*   __restrict__ doc_len,  int B,
    float*       __restrict__ out)
{
    float s = 0.0f;
    for (int i = threadIdx.x; i < npart; i += BLOCK)
        s += partials[i];

    int len = 0;
    for (int i = threadIdx.x; i < B; i += BLOCK)
        len += doc_len[i];

    #pragma unroll
    for (int off = 32; off > 0; off >>= 1) {
        s   += __shfl_down(s, off, 64);
        len += __shfl_down(len, off, 64);
    }

    __shared__ float fsum[BLOCK / 64];
    __shared__ int   isum[BLOCK / 64];
    const int lane = threadIdx.x & 63;
    const int wid  = threadIdx.x >> 6;
    if (lane == 0) { fsum[wid] = s; isum[wid] = len; }
    __syncthreads();
    if (threadIdx.x == 0) {
        float fs = 0.0f; int is = 0;
        #pragma unroll
        for (int w = 0; w < BLOCK / 64; ++w) { fs += fsum[w]; is += isum[w]; }
        out[0] = fs / (float)is;
    }
}

extern "C" void kernel_launch(void* const* d_in, const int* in_sizes, int n_in,
                              void* d_out, int out_size, void* d_ws, size_t ws_size,
                              hipStream_t stream)
{
    const float* y_true  = (const float*)d_in[0];
    const float* y_pred  = (const float*)d_in[1];
    const int*   doc_len = (const int*)d_in[2];
    float*       out     = (float*)d_out;
    float*       ws      = (float*)d_ws;

    const int B = in_sizes[2];
    const int L = in_sizes[0] / (2 * B);
    const int chunks_per_row = (L + POS_PER_BLOCK - 1) / POS_PER_BLOCK;
    const int npart = B * chunks_per_row;

    ce_main<<<dim3(npart), BLOCK, 0, stream>>>(y_true, y_pred, doc_len, ws, L, chunks_per_row);
    ce_finalize<<<dim3(1), BLOCK, 0, stream>>>(ws, npart, doc_len, B, out);
}